// Round 14
// baseline (109.200 us; speedup 1.0000x reference)
//
#include <hip/hip_runtime.h>

// ActorGCN collapsed-linear, split pipeline, 6 dispatches.
// Identity: A(xW) = (Ax)W; BN stats of h = yW+b reduce to the 20x20
// covariance of y = A x. Hidden [N,1024] never materialized.
//
// Round 14 (baseline r12 = 104.8us; r13 pk-atomic: global_atomic_pk_add_f32
// does NOT exist on gfx950 — f32 atomics are scalar-only):
//  - scatter accumulates z[d] = sum dinv[s]*x[s]  (dinv[d] factored out ->
//    no deg[d] gather in the hot loop); y_full = dinv*(z + dinv*x) applied
//    downstream where deg[row] is loaded anyway.
//  - stats no longer writes y_full back (-16.6MB); k_out recomputes it from
//    (z, x, deg) directly (x is L3-hot).
//  - y-zeroing moved from k_init into k_deg_acc (independent buffers, no
//    ordering hazard); k_init is now ~1MB.
//  - deg stored WITHOUT self-loop (zeroed, +1 at use sites).
// Pipeline: K1 init | K2 deg_acc(+zero z) | K3 scatter | K4 stats (no wb,
// reg-light) | K5 finalize (1 block, reg-heavy) | K6 out (recompute y_full).
//
// Workspace (floats): deg N | z 20N | stats 256 | params 64.

#define F 20
#define NSTAT 230
#define SROWS 256
#define BSZ 256

__global__ void k_init(float* __restrict__ deg, float* __restrict__ stats, int N) {
  int i = blockIdx.x * blockDim.x + threadIdx.x;
  if (i < N) deg[i] = 0.f;  // self-loop added at use: deg_true = deg + 1
  if (i < 256) stats[i] = 0.f;
}

// zero z (16.6MB, float4) + degree histogram atomics. z and deg are disjoint
// buffers, so intra-kernel ordering doesn't matter.
__global__ void k_deg_acc(const int* __restrict__ dst, float* __restrict__ deg,
                          float4* __restrict__ z4, int E, int N) {
  int i = blockIdx.x * blockDim.x + threadIdx.x;
  if (i < N * 5) z4[i] = make_float4(0.f, 0.f, 0.f, 0.f);
  if (i < E) atomicAdd(&deg[dst[i]], 1.0f);
}

// thread per (edge, feature), f-major (round-6 lesson: one-edge-per-lane
// layouts thrash L2 — a wave here spans ~3 rows, ~7 lines per atomic instr).
// z[d,f] += rsqrt(deg[s]+1) * x[s,f]   — no deg[d] gather.
__global__ void k_scatter(const int* __restrict__ src, const int* __restrict__ dst,
                          const float* __restrict__ deg,
                          const float* __restrict__ state,
                          const float* __restrict__ edge_attr,
                          float* __restrict__ z, int E, int Ns) {
  int tid = blockIdx.x * blockDim.x + threadIdx.x;
  if (tid >= E * F) return;
  int e = tid / F;
  int f = tid - e * F;
  int s = src[e];
  int d = dst[e];
  float ns = rsqrtf(deg[s] + 1.0f);
  int xi = s * F + f;
  int sb = Ns * F;
  float x = (xi < sb) ? state[xi] : edge_attr[xi - sb];
  atomicAdd(&z[(size_t)d * F + f], ns * x);
}

// Per 256-row block: build y_full = dinv*(z + dinv*x) in LDS (float4 staging,
// NO writeback), then 20 col sums + 210 upper-tri moments, one atomicAdd per
// stat per block. Register-light (round-11 lesson: keep finalize out).
__global__ __launch_bounds__(BSZ) void k_stats(
    const float* __restrict__ state, const float* __restrict__ edge_attr,
    const float* __restrict__ deg, const float* __restrict__ z,
    float* __restrict__ stats, int N, int Ns) {
  __shared__ float lds[SROWS * F];  // 20 KB
  int t = threadIdx.x;

  long rowbase = (long)blockIdx.x * SROWS;
  for (int i4 = t; i4 < SROWS * 5; i4 += BSZ) {
    int rl = i4 / 5;
    int q = i4 - rl * 5;
    long row = rowbase + rl;
    float4 v = make_float4(0.f, 0.f, 0.f, 0.f);
    if (row < N) {
      long gi = row * F + q * 4;
      float4 zv = *reinterpret_cast<const float4*>(z + gi);
      const float* xrow = (row < (long)Ns) ? (state + row * F)
                                           : (edge_attr + (row - Ns) * F);
      float4 xv = *reinterpret_cast<const float4*>(xrow + q * 4);
      float di = rsqrtf(deg[row] + 1.0f);
      v.x = di * (zv.x + di * xv.x);
      v.y = di * (zv.y + di * xv.y);
      v.z = di * (zv.z + di * xv.z);
      v.w = di * (zv.w + di * xv.w);
    }
    *reinterpret_cast<float4*>(lds + i4 * 4) = v;
  }
  __syncthreads();

  if (t < F) {
    float a0 = 0.f, a1 = 0.f, a2 = 0.f, a3 = 0.f;
    for (int r = 0; r < SROWS; r += 4) {
      a0 += lds[(r + 0) * F + t];
      a1 += lds[(r + 1) * F + t];
      a2 += lds[(r + 2) * F + t];
      a3 += lds[(r + 3) * F + t];
    }
    atomicAdd(&stats[t], (a0 + a1) + (a2 + a3));
  } else if (t < NSTAT) {
    int k = t - F, i = 0;
    while (k >= F - i) { k -= F - i; i++; }
    int ci = i, cj = i + k;
    float a0 = 0.f, a1 = 0.f, a2 = 0.f, a3 = 0.f;
    for (int r = 0; r < SROWS; r += 4) {
      a0 += lds[(r + 0) * F + ci] * lds[(r + 0) * F + cj];
      a1 += lds[(r + 1) * F + ci] * lds[(r + 1) * F + cj];
      a2 += lds[(r + 2) * F + ci] * lds[(r + 2) * F + cj];
      a3 += lds[(r + 3) * F + ci] * lds[(r + 3) * F + cj];
    }
    atomicAdd(&stats[t], (a0 + a1) + (a2 + a3));
  }
}

// Single block, 256 threads, launch_bounds(256,1): 4 waves -> up to 512
// VGPR/thread; w[4][20] + m0[20] + m1[20] live in registers (round-4 proven).
__global__ __launch_bounds__(256, 1) void k_finalize(
    const float* __restrict__ stats,
    const float* __restrict__ W_gcn,
    const float* __restrict__ gamma,
    const float* __restrict__ beta,
    const float* __restrict__ W_lin,
    const float* __restrict__ b_lin,
    float* __restrict__ params,
    int N, int H) {
  __shared__ float Cu_s[210];
  __shared__ float ybar_s[F];
  __shared__ float part[4][44];
  int t = threadIdx.x;
  int lane = t & 63;
  int wv = t >> 6;
  float invN = 1.0f / (float)N;
  if (t < F) ybar_s[t] = stats[t] * invN;
  __syncthreads();
  if (t < 210) {
    int k = t, i = 0;
    while (k >= F - i) { k -= F - i; i++; }
    int j = i + k;
    float cv = stats[F + t] * invN - ybar_s[i] * ybar_s[j];
    Cu_s[t] = (i == j) ? cv : 2.0f * cv;  // fold symmetry factor
  }
  __syncthreads();

  float m0[F], m1[F];
  #pragma unroll
  for (int f = 0; f < F; ++f) { m0[f] = 0.f; m1[f] = 0.f; }
  float d0 = 0.f, d1 = 0.f;

  for (int hb = 0; hb < H; hb += 4 * 256) {
    float w[4][F];
    float var[4];
    int hh[4];
    bool act[4];
    #pragma unroll
    for (int c = 0; c < 4; ++c) {
      int h = hb + c * 256 + t;
      act[c] = (h < H);
      hh[c] = act[c] ? h : 0;
      var[c] = 0.f;
      #pragma unroll
      for (int f = 0; f < F; ++f) {
        float x = W_gcn[f * H + hh[c]];  // coalesced over t
        w[c][f] = act[c] ? x : 0.f;
      }
    }
    int p = 0;
    #pragma unroll
    for (int i = 0; i < F; ++i) {
      #pragma unroll
      for (int j = i; j < F; ++j) {
        float cu = Cu_s[p];  // uniform broadcast, reused 4x
        ++p;
        #pragma unroll
        for (int c = 0; c < 4; ++c) var[c] += cu * (w[c][i] * w[c][j]);
      }
    }
    #pragma unroll
    for (int c = 0; c < 4; ++c) {
      float sg = act[c] ? (gamma[hh[c]] * rsqrtf(var[c] + 1e-5f)) : 0.f;
      float wl0 = W_lin[hh[c] * 2 + 0], wl1 = W_lin[hh[c] * 2 + 1];
      float s0 = sg * wl0, s1 = sg * wl1;
      #pragma unroll
      for (int f = 0; f < F; ++f) { m0[f] += w[c][f] * s0; m1[f] += w[c][f] * s1; }
      float bt = act[c] ? beta[hh[c]] : 0.f;
      d0 += bt * wl0;
      d1 += bt * wl1;
    }
  }

  #pragma unroll
  for (int f = 0; f < F; ++f) {
    float v0 = m0[f], v1 = m1[f];
    #pragma unroll
    for (int off = 32; off; off >>= 1) {
      v0 += __shfl_xor(v0, off);
      v1 += __shfl_xor(v1, off);
    }
    if (lane == 0) { part[wv][2 * f] = v0; part[wv][2 * f + 1] = v1; }
  }
  #pragma unroll
  for (int off = 32; off; off >>= 1) {
    d0 += __shfl_xor(d0, off);
    d1 += __shfl_xor(d1, off);
  }
  if (lane == 0) { part[wv][40] = d0; part[wv][41] = d1; }
  __syncthreads();

  if (t < 42) {
    float acc = 0.f;
    for (int w2 = 0; w2 < 4; ++w2) acc += part[w2][t];
    if (t >= 40) acc += b_lin[t - 40];
    params[t] = acc;
  } else if (t < 62) {
    params[t] = ybar_s[t - 42];
  }
}

// thread per node: recompute y_full = dinv*(z + dinv*x) in regs, then
// logits = (y-ybar)@M + d; relu; 2-way softmax.
__global__ void k_out(const float* __restrict__ state,
                      const float* __restrict__ edge_attr,
                      const float* __restrict__ deg,
                      const float* __restrict__ z,
                      const float* __restrict__ params,
                      float* __restrict__ out, int N, int Ns) {
  __shared__ float P[64];
  if (threadIdx.x < 62) P[threadIdx.x] = params[threadIdx.x];
  __syncthreads();
  int n = blockIdx.x * blockDim.x + threadIdx.x;
  if (n >= N) return;
  const float4* zr4 = reinterpret_cast<const float4*>(z + (size_t)n * F);
  const float* xrow = (n < Ns) ? (state + (size_t)n * F)
                               : (edge_attr + (size_t)(n - Ns) * F);
  const float4* xr4 = reinterpret_cast<const float4*>(xrow);
  float di = rsqrtf(deg[n] + 1.0f);
  float l0 = P[40], l1 = P[41];
  #pragma unroll
  for (int k = 0; k < 5; ++k) {
    float4 zq = zr4[k];
    float4 xq = xr4[k];
    float vv[4];
    vv[0] = di * (zq.x + di * xq.x);
    vv[1] = di * (zq.y + di * xq.y);
    vv[2] = di * (zq.z + di * xq.z);
    vv[3] = di * (zq.w + di * xq.w);
    #pragma unroll
    for (int u = 0; u < 4; ++u) {
      int f = 4 * k + u;
      float dv = vv[u] - P[42 + f];
      l0 += dv * P[2 * f + 0];
      l1 += dv * P[2 * f + 1];
    }
  }
  l0 = fmaxf(l0, 0.f);
  l1 = fmaxf(l1, 0.f);
  float m = fmaxf(l0, l1);
  float e0 = __expf(l0 - m), e1 = __expf(l1 - m);
  float inv = 1.0f / (e0 + e1);
  float2 o2;
  o2.x = e0 * inv;
  o2.y = e1 * inv;
  reinterpret_cast<float2*>(out)[n] = o2;
}

extern "C" void kernel_launch(void* const* d_in, const int* in_sizes, int n_in,
                              void* d_out, int out_size, void* d_ws, size_t ws_size,
                              hipStream_t stream) {
  const float* state     = (const float*)d_in[0];
  const float* edge_attr = (const float*)d_in[1];
  const int*   eidx      = (const int*)d_in[2];
  const float* W_gcn     = (const float*)d_in[3];
  // d_in[4] = b_gcn: cancels inside batchnorm, unused.
  const float* gamma     = (const float*)d_in[5];
  const float* beta      = (const float*)d_in[6];
  const float* W_lin     = (const float*)d_in[7];
  const float* b_lin     = (const float*)d_in[8];
  float* out = (float*)d_out;

  int Ns = in_sizes[0] / F;
  int E  = in_sizes[2] / 2;
  int N  = Ns + in_sizes[1] / F;
  int H  = in_sizes[4];

  const int* src = eidx;
  const int* dst = eidx + E;

  float* ws     = (float*)d_ws;
  float* deg    = ws;
  float* z      = ws + N;
  float* stats  = z + (size_t)N * F;
  float* params = stats + 256;

  int nblk = (N + SROWS - 1) / SROWS;

  k_init<<<(N + BSZ - 1) / BSZ, BSZ, 0, stream>>>(deg, stats, N);
  k_deg_acc<<<(N * 5 + BSZ - 1) / BSZ, BSZ, 0, stream>>>(
      dst, deg, (float4*)z, E, N);
  k_scatter<<<(E * F + BSZ - 1) / BSZ, BSZ, 0, stream>>>(
      src, dst, deg, state, edge_attr, z, E, Ns);
  k_stats<<<nblk, BSZ, 0, stream>>>(state, edge_attr, deg, z, stats, N, Ns);
  k_finalize<<<1, 256, 0, stream>>>(stats, W_gcn, gamma, beta, W_lin, b_lin,
                                    params, N, H);
  k_out<<<(N + BSZ - 1) / BSZ, BSZ, 0, stream>>>(
      state, edge_attr, deg, z, params, out, N, Ns);
}